// Round 3
// baseline (748.469 us; speedup 1.0000x reference)
//
#include <hip/hip_runtime.h>
#include <math.h>

#define NLEV 16
#define TBL (1u << 19)
#define TMASK (TBL - 1u)
#define PR1 2654435761u
#define PR2 805459861u

typedef float f2_t __attribute__((ext_vector_type(2)));
typedef float f4_t __attribute__((ext_vector_type(4)));

struct LevelParams {
    float scale[NLEV];
    unsigned int res[NLEV];
    unsigned int dense_mask;  // bit l set => dense (stride) indexing
};

// Computes one (point, level) pair. Pairing trick: the two x-corners share
// one aligned 16B table chunk whenever the even-x corner's index is known
// (hashed: idx(x+1)=idx(x)^1 for even x since prime[0]==1 and x enters by
// XOR; dense: idx(x+1)=idx(x)+1). Odd-parity lanes add one predicated
// float2 load. Cuts lane-addresses/point-level from 8 to ~6.
__device__ __forceinline__ void encode_pl(
    float c0, float c1, float c2, float s, unsigned int res, bool dense,
    const float* __restrict__ tl, float& acc0, float& acc1)
{
    // match reference op order: coords01 = (c+1)/2; pos = coords01*scale + 0.5
    float p0 = ((c0 + 1.0f) * 0.5f) * s + 0.5f;
    float p1 = ((c1 + 1.0f) * 0.5f) * s + 0.5f;
    float p2 = ((c2 + 1.0f) * 0.5f) * s + 0.5f;
    float fp0 = floorf(p0), fp1 = floorf(p1), fp2 = floorf(p2);
    float f0 = p0 - fp0, f1 = p1 - fp1, f2 = p2 - fp2;
    unsigned int g0 = (unsigned int)fp0;
    unsigned int g1 = (unsigned int)fp1;
    unsigned int g2 = (unsigned int)fp2;

    float wy[2] = {1.0f - f1, f1};
    float wz[2] = {1.0f - f2, f2};
    float w0 = 1.0f - f0;

    acc0 = 0.0f; acc1 = 0.0f;

    if (dense) {
        unsigned int res2 = res * res;
        #pragma unroll
        for (int zc = 0; zc < 2; ++zc) {
            #pragma unroll
            for (int yc = 0; yc < 2; ++yc) {
                unsigned int b = (g1 + (unsigned)yc) * res + (g2 + (unsigned)zc) * res2;
                unsigned int j0 = g0 + b;           // idx of x-corner 0; j0+1 is x-corner 1; both < T
                bool odd = (j0 & 1u) != 0u;
                f4_t q = *reinterpret_cast<const f4_t*>(tl + (size_t)(j0 & ~1u) * 2u);
                f2_t ex;
                if (odd) ex = *reinterpret_cast<const f2_t*>(tl + (size_t)(j0 + 1u) * 2u);
                float e0x = odd ? q.z : q.x, e0y = odd ? q.w : q.y;   // entry j0
                float e1x = odd ? ex.x : q.z, e1y = odd ? ex.y : q.w; // entry j0+1
                float wyz = wy[yc] * wz[zc];
                acc0 += wyz * (w0 * e0x + f0 * e1x);
                acc1 += wyz * (w0 * e0y + f0 * e1y);
            }
        }
    } else {
        unsigned int hy[2] = {g1 * PR1, (g1 + 1u) * PR1};
        unsigned int hz[2] = {g2 * PR2, (g2 + 1u) * PR2};
        bool godd = (g0 & 1u) != 0u;
        unsigned int xe = g0 + (godd ? 1u : 0u);    // the even x-corner
        #pragma unroll
        for (int zc = 0; zc < 2; ++zc) {
            #pragma unroll
            for (int yc = 0; yc < 2; ++yc) {
                unsigned int hyz = hy[yc] ^ hz[zc];
                unsigned int je = (xe ^ hyz) & TMASK;  // idx(xe); idx(xe+1)=je^1 in same 16B
                f4_t q = *reinterpret_cast<const f4_t*>(tl + (size_t)(je & ~1u) * 2u);
                f2_t ex;
                if (godd) ex = *reinterpret_cast<const f2_t*>(tl + (size_t)((g0 ^ hyz) & TMASK) * 2u);
                bool hi = (je & 1u) != 0u;
                float fex = hi ? q.z : q.x, fey = hi ? q.w : q.y;  // entry je   (= corner xe)
                float fox = hi ? q.x : q.z, foy = hi ? q.y : q.w;  // entry je^1 (= corner xe+1)
                // corner x=g0:   even -> fe ; odd -> ex
                // corner x=g0+1: even -> fo ; odd -> fe
                float e0x = godd ? ex.x : fex, e0y = godd ? ex.y : fey;
                float e1x = godd ? fex : fox, e1y = godd ? fey : foy;
                float wyz = wy[yc] * wz[zc];
                acc0 += wyz * (w0 * e0x + f0 * e1x);
                acc1 += wyz * (w0 * e0y + f0 * e1y);
            }
        }
    }
}

// Level-major: blockIdx = l * blocksPerLevel + chunk -> dispatch window covers
// ~1-2 levels -> each XCD's 4 MB L2 holds the active level's table.
__global__ __launch_bounds__(256) void hashenc_level_kernel(
    const float* __restrict__ coords,
    const float* __restrict__ table,
    float* __restrict__ ws,           // [L][N][2]
    LevelParams lp, int npts, int blocksPerLevel)
{
    int l = blockIdx.x / blocksPerLevel;
    int n = (blockIdx.x - l * blocksPerLevel) * 256 + threadIdx.x;
    if (n >= npts) return;

    float c0 = coords[3 * n + 0];
    float c1 = coords[3 * n + 1];
    float c2 = coords[3 * n + 2];

    const float* tl = table + (size_t)l * (size_t)TBL * 2u;
    float acc0, acc1;
    encode_pl(c0, c1, c2, lp.scale[l], lp.res[l],
              (lp.dense_mask >> l) & 1u, tl, acc0, acc1);

    f2_t v; v.x = acc0; v.y = acc1;
    // non-temporal: avoid leaving ws dirty in this XCD's L2 (transpose reads
    // it from a different XCD; dirty-probe path measured ~2x slower).
    __builtin_nontemporal_store(v, reinterpret_cast<f2_t*>(ws) + (size_t)l * npts + n);
}

// [L][N][2] -> [N][L*2]
__global__ __launch_bounds__(256) void transpose_kernel(
    const float* __restrict__ ws, float* __restrict__ out, int npts)
{
    int n = blockIdx.x * 256 + threadIdx.x;
    if (n >= npts) return;
    float buf[32];
    const f2_t* wsp = reinterpret_cast<const f2_t*>(ws);
    #pragma unroll
    for (int l = 0; l < NLEV; ++l) {
        f2_t f = __builtin_nontemporal_load(wsp + (size_t)l * npts + n);
        buf[2 * l] = f.x;
        buf[2 * l + 1] = f.y;
    }
    f4_t* op = reinterpret_cast<f4_t*>(out + (size_t)n * 32);
    #pragma unroll
    for (int i = 0; i < 8; ++i) {
        f4_t v; v.x = buf[4*i]; v.y = buf[4*i+1]; v.z = buf[4*i+2]; v.w = buf[4*i+3];
        __builtin_nontemporal_store(v, op + i);
    }
}

// Fallback: point-major, direct out writes (used only if ws too small).
__global__ __launch_bounds__(256) void hashenc_kernel(
    const float* __restrict__ coords,
    const float* __restrict__ table,
    float* __restrict__ out,
    LevelParams lp, int npts)
{
    int gid = blockIdx.x * 256 + threadIdx.x;
    int n = gid >> 4;
    if (n >= npts) return;
    int l = gid & 15;
    float c0 = coords[3 * n + 0];
    float c1 = coords[3 * n + 1];
    float c2 = coords[3 * n + 2];
    const float* tl = table + (size_t)l * (size_t)TBL * 2u;
    float acc0, acc1;
    encode_pl(c0, c1, c2, lp.scale[l], lp.res[l],
              (lp.dense_mask >> l) & 1u, tl, acc0, acc1);
    float2* op = reinterpret_cast<float2*>(out + (size_t)n * 32 + (size_t)l * 2);
    *op = make_float2(acc0, acc1);
}

extern "C" void kernel_launch(void* const* d_in, const int* in_sizes, int n_in,
                              void* d_out, int out_size, void* d_ws, size_t ws_size,
                              hipStream_t stream) {
    const float* coords = (const float*)d_in[0];
    const float* table  = (const float*)d_in[1];
    float* out = (float*)d_out;
    int npts = in_sizes[0] / 3;

    LevelParams lp;
    const double growth = exp((log(2048.0) - log(16.0)) / 15.0);
    unsigned int dm = 0;
    for (int l = 0; l < NLEV; ++l) {
        double sc = 16.0 * pow(growth, (double)l) - 1.0;
        lp.scale[l] = (float)sc;
        long long r = (long long)ceil(sc) + 1;
        lp.res[l] = (unsigned int)r;
        if (r * r * r <= (long long)TBL) dm |= (1u << l);
    }
    lp.dense_mask = dm;

    size_t ws_needed = (size_t)npts * NLEV * 2 * sizeof(float);
    if (ws_size >= ws_needed) {
        int blocksPerLevel = (npts + 255) / 256;
        hipLaunchKernelGGL(hashenc_level_kernel,
                           dim3(blocksPerLevel * NLEV), dim3(256), 0, stream,
                           coords, table, (float*)d_ws, lp, npts, blocksPerLevel);
        hipLaunchKernelGGL(transpose_kernel,
                           dim3(blocksPerLevel), dim3(256), 0, stream,
                           (const float*)d_ws, out, npts);
    } else {
        int total = npts * NLEV;
        int blocks = (total + 255) / 256;
        hipLaunchKernelGGL(hashenc_kernel, dim3(blocks), dim3(256), 0, stream,
                           coords, table, out, lp, npts);
    }
}

// Round 4
// 463.999 us; speedup vs baseline: 1.6131x; 1.6131x over previous
//
#include <hip/hip_runtime.h>
#include <math.h>

#define NLEV 16
#define TBL (1u << 19)
#define TMASK (TBL - 1u)
#define PR1 2654435761u
#define PR2 805459861u

typedef float f2_t __attribute__((ext_vector_type(2)));
typedef float f4_t __attribute__((ext_vector_type(4)));

struct LevelParams {
    float scale[NLEV];
    unsigned int res[NLEV];
    unsigned int dense_mask;  // bit l set => dense (stride) indexing
};

// One (point, level). x-corner pairing: both x-corners usually live in one
// aligned 16B float4 (hashed: idx(x^1)=idx(x)^1; dense: idx+1). Odd-x points
// need one extra float2 line. Avg ~6 L1 line-touches per point-level.
__device__ __forceinline__ void encode_pl(
    float c0, float c1, float c2, float s, unsigned int res, bool dense,
    const float* __restrict__ tl, float& acc0, float& acc1)
{
    // match reference op order: coords01 = (c+1)/2; pos = coords01*scale + 0.5
    float p0 = ((c0 + 1.0f) * 0.5f) * s + 0.5f;
    float p1 = ((c1 + 1.0f) * 0.5f) * s + 0.5f;
    float p2 = ((c2 + 1.0f) * 0.5f) * s + 0.5f;
    float fp0 = floorf(p0), fp1 = floorf(p1), fp2 = floorf(p2);
    float f0 = p0 - fp0, f1 = p1 - fp1, f2 = p2 - fp2;
    unsigned int g0 = (unsigned int)fp0;
    unsigned int g1 = (unsigned int)fp1;
    unsigned int g2 = (unsigned int)fp2;

    float wy[2] = {1.0f - f1, f1};
    float wz[2] = {1.0f - f2, f2};
    float w0 = 1.0f - f0;

    acc0 = 0.0f; acc1 = 0.0f;

    if (dense) {
        unsigned int res2 = res * res;
        #pragma unroll
        for (int zc = 0; zc < 2; ++zc) {
            #pragma unroll
            for (int yc = 0; yc < 2; ++yc) {
                unsigned int b = (g1 + (unsigned)yc) * res + (g2 + (unsigned)zc) * res2;
                unsigned int j0 = g0 + b;
                bool odd = (j0 & 1u) != 0u;
                f4_t q = *reinterpret_cast<const f4_t*>(tl + (size_t)(j0 & ~1u) * 2u);
                f2_t ex;
                if (odd) ex = *reinterpret_cast<const f2_t*>(tl + (size_t)(j0 + 1u) * 2u);
                float e0x = odd ? q.z : q.x, e0y = odd ? q.w : q.y;
                float e1x = odd ? ex.x : q.z, e1y = odd ? ex.y : q.w;
                float wyz = wy[yc] * wz[zc];
                acc0 += wyz * (w0 * e0x + f0 * e1x);
                acc1 += wyz * (w0 * e0y + f0 * e1y);
            }
        }
    } else {
        unsigned int hy[2] = {g1 * PR1, (g1 + 1u) * PR1};
        unsigned int hz[2] = {g2 * PR2, (g2 + 1u) * PR2};
        bool godd = (g0 & 1u) != 0u;
        unsigned int xe = g0 + (godd ? 1u : 0u);    // even x-corner
        #pragma unroll
        for (int zc = 0; zc < 2; ++zc) {
            #pragma unroll
            for (int yc = 0; yc < 2; ++yc) {
                unsigned int hyz = hy[yc] ^ hz[zc];
                unsigned int je = (xe ^ hyz) & TMASK;
                f4_t q = *reinterpret_cast<const f4_t*>(tl + (size_t)(je & ~1u) * 2u);
                f2_t ex;
                if (godd) ex = *reinterpret_cast<const f2_t*>(tl + (size_t)((g0 ^ hyz) & TMASK) * 2u);
                bool hi = (je & 1u) != 0u;
                float fex = hi ? q.z : q.x, fey = hi ? q.w : q.y;  // entry je   (= corner xe)
                float fox = hi ? q.x : q.z, foy = hi ? q.y : q.w;  // entry je^1 (= corner xe+1)
                float e0x = godd ? ex.x : fex, e0y = godd ? ex.y : fey;
                float e1x = godd ? fex : fox, e1y = godd ? fey : foy;
                float wyz = wy[yc] * wz[zc];
                acc0 += wyz * (w0 * e0x + f0 * e1x);
                acc1 += wyz * (w0 * e0y + f0 * e1y);
            }
        }
    }
}

// Level-major gather: dispatch window covers ~1-2 levels -> per-XCD L2 holds
// the active level's 4 MB table. NT store: ws is write-once, keep L2 clean.
__global__ __launch_bounds__(256) void hashenc_level_kernel(
    const float* __restrict__ coords,
    const float* __restrict__ table,
    float* __restrict__ ws,           // [L][N][2]
    LevelParams lp, int npts, int blocksPerLevel)
{
    int l = blockIdx.x / blocksPerLevel;
    int n = (blockIdx.x - l * blocksPerLevel) * 256 + threadIdx.x;
    if (n >= npts) return;

    float c0 = coords[3 * n + 0];
    float c1 = coords[3 * n + 1];
    float c2 = coords[3 * n + 2];

    const float* tl = table + (size_t)l * (size_t)TBL * 2u;
    float acc0, acc1;
    encode_pl(c0, c1, c2, lp.scale[l], lp.res[l],
              (lp.dense_mask >> l) & 1u, tl, acc0, acc1);

    f2_t v; v.x = acc0; v.y = acc1;
    __builtin_nontemporal_store(v, reinterpret_cast<f2_t*>(ws) + (size_t)l * npts + n);
}

// [L][N][2] -> [N][32] via LDS tile. Row stride 34 floats: phase-1 writes are
// 2-way bank aliases (free), phase-2 b64 reads 4-way (1.58x, not critical).
// Both global sides fully coalesced, regular (L2-merged) stores.
__global__ __launch_bounds__(256) void transpose_kernel(
    const float* __restrict__ ws, float* __restrict__ out, int npts)
{
    __shared__ float lds[256 * 34];
    int t = threadIdx.x;
    int p0 = blockIdx.x * 256;
    int n = p0 + t;

    if (n < npts) {
        #pragma unroll
        for (int l = 0; l < NLEV; ++l) {
            f2_t v = *(reinterpret_cast<const f2_t*>(ws) + (size_t)l * npts + n);
            *reinterpret_cast<f2_t*>(&lds[t * 34 + 2 * l]) = v;
        }
    }
    __syncthreads();

    // 256 points * 8 float4 = 2048 float4s, 8 per thread, coalesced.
    f4_t* ob = reinterpret_cast<f4_t*>(out + (size_t)p0 * 32);
    #pragma unroll
    for (int i = 0; i < 8; ++i) {
        int fi = i * 256 + t;
        int p = fi >> 3, c = fi & 7;
        if (p0 + p < npts) {
            f2_t a = *reinterpret_cast<const f2_t*>(&lds[p * 34 + c * 4]);
            f2_t b = *reinterpret_cast<const f2_t*>(&lds[p * 34 + c * 4 + 2]);
            f4_t v; v.x = a.x; v.y = a.y; v.z = b.x; v.w = b.y;
            ob[fi] = v;
        }
    }
}

// Fallback: point-major, direct out writes (used only if ws too small).
__global__ __launch_bounds__(256) void hashenc_kernel(
    const float* __restrict__ coords,
    const float* __restrict__ table,
    float* __restrict__ out,
    LevelParams lp, int npts)
{
    int gid = blockIdx.x * 256 + threadIdx.x;
    int n = gid >> 4;
    if (n >= npts) return;
    int l = gid & 15;
    float c0 = coords[3 * n + 0];
    float c1 = coords[3 * n + 1];
    float c2 = coords[3 * n + 2];
    const float* tl = table + (size_t)l * (size_t)TBL * 2u;
    float acc0, acc1;
    encode_pl(c0, c1, c2, lp.scale[l], lp.res[l],
              (lp.dense_mask >> l) & 1u, tl, acc0, acc1);
    float2* op = reinterpret_cast<float2*>(out + (size_t)n * 32 + (size_t)l * 2);
    *op = make_float2(acc0, acc1);
}

extern "C" void kernel_launch(void* const* d_in, const int* in_sizes, int n_in,
                              void* d_out, int out_size, void* d_ws, size_t ws_size,
                              hipStream_t stream) {
    const float* coords = (const float*)d_in[0];
    const float* table  = (const float*)d_in[1];
    float* out = (float*)d_out;
    int npts = in_sizes[0] / 3;

    LevelParams lp;
    const double growth = exp((log(2048.0) - log(16.0)) / 15.0);
    unsigned int dm = 0;
    for (int l = 0; l < NLEV; ++l) {
        double sc = 16.0 * pow(growth, (double)l) - 1.0;
        lp.scale[l] = (float)sc;
        long long r = (long long)ceil(sc) + 1;
        lp.res[l] = (unsigned int)r;
        if (r * r * r <= (long long)TBL) dm |= (1u << l);
    }
    lp.dense_mask = dm;

    size_t ws_needed = (size_t)npts * NLEV * 2 * sizeof(float);
    if (ws_size >= ws_needed) {
        int blocksPerLevel = (npts + 255) / 256;
        hipLaunchKernelGGL(hashenc_level_kernel,
                           dim3(blocksPerLevel * NLEV), dim3(256), 0, stream,
                           coords, table, (float*)d_ws, lp, npts, blocksPerLevel);
        hipLaunchKernelGGL(transpose_kernel,
                           dim3(blocksPerLevel), dim3(256), 0, stream,
                           (const float*)d_ws, out, npts);
    } else {
        int total = npts * NLEV;
        int blocks = (total + 255) / 256;
        hipLaunchKernelGGL(hashenc_kernel, dim3(blocks), dim3(256), 0, stream,
                           coords, table, out, lp, npts);
    }
}